// Round 11
// baseline (130.265 us; speedup 1.0000x reference)
//
#include <hip/hip_runtime.h>
#include <cstdint>

typedef _Float16 f16;
typedef f16 f16x2 __attribute__((ext_vector_type(2)));
typedef f16 f16x4 __attribute__((ext_vector_type(4)));
typedef f16 f16x8 __attribute__((ext_vector_type(8)));
typedef float f32x4 __attribute__((ext_vector_type(4)));
typedef float f32x16 __attribute__((ext_vector_type(16)));

#define MFMA16F(a, b, c) __builtin_amdgcn_mfma_f32_16x16x32_f16(a, b, c, 0, 0, 0)
#define MFMA32F(a, b, c) __builtin_amdgcn_mfma_f32_32x32x16_f16(a, b, c, 0, 0, 0)

static constexpr int N = 4096;    // 64*64 tokens
static constexpr int CDIM = 128;  // channels
static constexpr int NH = 4;      // heads
static constexpr int DH = 32;     // dim per head

__device__ __forceinline__ f16x2 cvt_pk(float a, float b) {
    return __builtin_bit_cast(f16x2, __builtin_amdgcn_cvt_pkrtz(a, b));
}

// ---------------- QKV projection (r8 verbatim: split-z, inline W convert) ---
__global__ __launch_bounds__(256) void proj_qkv(const float* __restrict__ x,
                                                const float* __restrict__ wq,
                                                const float* __restrict__ wk,
                                                const float* __restrict__ wv,
                                                f16* __restrict__ Q,
                                                f16* __restrict__ K,
                                                f16* __restrict__ V) {
    const int b = blockIdx.y;
    const int wt = blockIdx.z;
    const int n0 = blockIdx.x * 64;
    __shared__ __align__(16) f16 xT[64][136];   // [n][c], padded
    __shared__ __align__(16) f16 Wl[128 * 136]; // W rows padded to 136
    const int tid = threadIdx.x;
    const float* xb = x + (size_t)b * CDIM * N;
    const float* Wsrc = (wt == 0) ? wq : (wt == 1) ? wk : wv;
    const float wsc = (wt == 0) ? 0.17677669529663687f * 1.4426950408889634f : 1.0f;

    for (int i = tid; i < 512; i += 256) {  // 4 channels/iter -> b64 LDS writes
        const int n4 = (i & 15) * 4, c4 = (i >> 4) * 4;
        const float* xp = &xb[(size_t)c4 * N + n0 + n4];
        const float4 v0 = *(const float4*)(xp);
        const float4 v1 = *(const float4*)(xp + N);
        const float4 v2 = *(const float4*)(xp + 2 * N);
        const float4 v3 = *(const float4*)(xp + 3 * N);
        f16x4 w0 = {(f16)v0.x, (f16)v1.x, (f16)v2.x, (f16)v3.x};
        f16x4 w1 = {(f16)v0.y, (f16)v1.y, (f16)v2.y, (f16)v3.y};
        f16x4 w2 = {(f16)v0.z, (f16)v1.z, (f16)v2.z, (f16)v3.z};
        f16x4 w3 = {(f16)v0.w, (f16)v1.w, (f16)v2.w, (f16)v3.w};
        *(f16x4*)&xT[n4 + 0][c4] = w0;
        *(f16x4*)&xT[n4 + 1][c4] = w1;
        *(f16x4*)&xT[n4 + 2][c4] = w2;
        *(f16x4*)&xT[n4 + 3][c4] = w3;
    }
    for (int i = tid; i < 2048; i += 256) {  // stage W, f32 -> f16 inline
        int row = i >> 4, c8 = (i & 15) * 8;
        const float4 fa = *(const float4*)&Wsrc[row * 128 + c8];
        const float4 fb = *(const float4*)&Wsrc[row * 128 + c8 + 4];
        f16x8 v8 = {(f16)(fa.x * wsc), (f16)(fa.y * wsc), (f16)(fa.z * wsc), (f16)(fa.w * wsc),
                    (f16)(fb.x * wsc), (f16)(fb.y * wsc), (f16)(fb.z * wsc), (f16)(fb.w * wsc)};
        *(f16x8*)&Wl[row * 136 + c8] = v8;
    }
    __syncthreads();

    const int lane = tid & 63, w = tid >> 6;
    const int cr = lane & 15, quad = lane >> 4;
    const int sg = ((quad & 1) << 1) | (quad >> 1);  // V slot-group of quad

    for (int nt = 0; nt < 4; ++nt) {
        f16x8 bfr[4];
#pragma unroll
        for (int ks = 0; ks < 4; ++ks)
            bfr[ks] = *(const f16x8*)&xT[nt * 16 + cr][ks * 32 + quad * 8];
#pragma unroll
        for (int ot2 = 0; ot2 < 2; ++ot2) {
            int ot = w * 2 + ot2;
            f32x4 acc = {0.f, 0.f, 0.f, 0.f};
            if (wt < 2) {
                // D[o][n]: row(o)=ot*16+quad*4+r, col(n)=cr
#pragma unroll
                for (int ks = 0; ks < 4; ++ks) {
                    f16x8 afr = *(const f16x8*)&Wl[(ot * 16 + cr) * 136 + ks * 32 + quad * 8];
                    acc = MFMA16F(afr, bfr[ks], acc);
                }
                f16* dst = (wt == 0) ? Q : K;
                int n = n0 + nt * 16 + cr;
                int o0 = ot * 16 + quad * 4, hh = o0 >> 5, d0 = o0 & 31;
                f16x4 v4 = {(f16)acc[0], (f16)acc[1], (f16)acc[2], (f16)acc[3]};
                *(f16x4*)(dst + (((size_t)(b * NH + hh) * N + n) * DH + d0)) = v4;
            } else {
                // swapped: D[key][o]: row(key off)=quad*4+r, col(o)=ot*16+cr
#pragma unroll
                for (int ks = 0; ks < 4; ++ks) {
                    f16x8 afr = *(const f16x8*)&Wl[(ot * 16 + cr) * 136 + ks * 32 + quad * 8];
                    acc = MFMA16F(bfr[ks], afr, acc);
                }
                int o = ot * 16 + cr, hh = o >> 5, d = o & 31;
                f16x4 v4 = {(f16)acc[0], (f16)acc[1], (f16)acc[2], (f16)acc[3]};
                *(f16x4*)(V + ((size_t)(b * NH + hh) * 64 + blockIdx.x) * 2048 +
                          d * 64 + nt * 16 + sg * 4) = v4;
            }
        }
    }
}

// ---------------- flash attention: LDS-V + direct-global-K hybrid -----------
// K's LDS round-trip was an identity copy (each wave's fragment is a
// contiguous b128 in K's [n][32] layout) and wave-pairs read identical
// fragments -> load K straight from L1/L2 (r2's proven addressing). V keeps
// the LDS staging pipeline (its permuted layout needs the redistribution)
// and the 2-barrier pacing. Halves the LDS pipe (~17 -> ~9 us/CU).
__global__ __launch_bounds__(512, 4) void flash(const f16* __restrict__ Q,
                                                const f16* __restrict__ K,
                                                const f16* __restrict__ V,
                                                f16* __restrict__ O) {
    const int gid = blockIdx.x;
    const int bh = gid & 15;
    const int qblk = gid >> 4;  // 0..31
    const int tid = threadIdx.x;
    const int w = tid >> 6, lane = tid & 63;
    const int l31 = lane & 31, h = lane >> 5;
    const int qg = w & 1, kh = w >> 1;
    const int qbase = qblk * 128 + qg * 64;

    __shared__ __align__(16) f16 Vl[4][32 * 72];   // d rows stride 72 (18432 B)
    __shared__ __align__(16) float red[6 * 64 * 20];  // 30720 B epilogue
    __shared__ float lred[8][64];
    __shared__ float lred1[8][64];

    const f16* Qb = Q + (size_t)bh * N * DH;
    const f16* Kb = K + (size_t)bh * N * DH;
    const f16* Vt = V + (size_t)bh * 64 * 2048;

    const int qtr = tid >> 7, t = tid & 127;
    const f16* vsrc = Vt + (size_t)(qtr * 16) * 2048 + t * 16;
    f16* vdst = &Vl[qtr][(t >> 2) * 72 + (t & 3) * 16];

    f16x8 qf[2][2];  // [qs][d-half]
#pragma unroll
    for (int qs = 0; qs < 2; ++qs)
#pragma unroll
        for (int dh = 0; dh < 2; ++dh)
            qf[qs][dh] = *(const f16x8*)&Qb[(qbase + qs * 32 + l31) * DH + dh * 16 + h * 8];

    const f16x2 C3 = {(f16)0.05550411f, (f16)0.05550411f};
    const f16x2 C2 = {(f16)0.24022651f, (f16)0.24022651f};
    const f16x2 C1 = {(f16)0.69314718f, (f16)0.69314718f};
    const f16x2 ONE2 = {(f16)1.0f, (f16)1.0f};

    f32x16 out[2] = {};          // [qs]: out^T[d=row][q=col]
    float lsum[2] = {0.f, 0.f};  // per-lane partial normalizer

    // K fragment base for this wave's key quarter (r2 addressing, verified):
    // key row = kh*1024 + kt*64 + g2*32 + l31, d offset = h*8 (+16 for half 1)
    const f16* Kg = Kb + ((size_t)(kh * 1024 + l31) * 32 + h * 8);

    // prefetch V tile 0
    f16x8 vr0 = *(const f16x8*)(vsrc);
    f16x8 vr1 = *(const f16x8*)(vsrc + 8);

    for (int kt = 0; kt < 16; ++kt) {
        __syncthreads();
        *(f16x8*)(vdst)     = vr0;
        *(f16x8*)(vdst + 8) = vr1;
        __syncthreads();
        // K loads for this kt: straight from global (L1-resident for the
        // 4 consuming waves); issued before the V prefetch for distance.
        const f16* kp = Kg + (size_t)kt * 2048;
        f16x8 kfA0 = *(const f16x8*)(kp);
        f16x8 kfA1 = *(const f16x8*)(kp + 16);
        f16x8 kfB0 = *(const f16x8*)(kp + 1024);
        f16x8 kfB1 = *(const f16x8*)(kp + 1024 + 16);
        if (kt < 15) {
            const size_t off = (size_t)(kt + 1) * 2048;
            vr0 = *(const f16x8*)(vsrc + off);
            vr1 = *(const f16x8*)(vsrc + off + 8);
        }
        const f16* Vc = &Vl[kh][0];

#pragma unroll
        for (int g2 = 0; g2 < 2; ++g2) {
            f16x8 kf0 = g2 ? kfB0 : kfA0;
            f16x8 kf1 = g2 ? kfB1 : kfA1;
            f16x8 av0 = *(const f16x8*)&Vc[l31 * 72 + g2 * 32 + h * 8];
            f16x8 av1 = *(const f16x8*)&Vc[l31 * 72 + g2 * 32 + 16 + h * 8];

            // --- both qs QK^T blocks (independent chains) ---
            f32x16 sc0 = {};
            f32x16 sc1 = {};
            sc0 = MFMA32F(kf0, qf[0][0], sc0);
            sc1 = MFMA32F(kf0, qf[1][0], sc1);
            sc0 = MFMA32F(kf1, qf[0][1], sc0);
            sc1 = MFMA32F(kf1, qf[1][1], sc1);

            // --- both exp polys, interleaved ---
            f16x2 p0[8], p1[8];
#pragma unroll
            for (int i = 0; i < 8; ++i) {
                f16x2 x0 = cvt_pk(sc0[2 * i], sc0[2 * i + 1]);
                f16x2 x1 = cvt_pk(sc1[2 * i], sc1[2 * i + 1]);
                f16x2 t0 = x0 * C3 + C2;
                f16x2 t1 = x1 * C3 + C2;
                t0 = x0 * t0 + C1;
                t1 = x1 * t1 + C1;
                p0[i] = x0 * t0 + ONE2;
                p1[i] = x1 * t1 + ONE2;
            }
            struct P4 { f16x2 a, b, c, d; };
            P4 q0a{p0[0], p0[1], p0[2], p0[3]};
            P4 q0b{p0[4], p0[5], p0[6], p0[7]};
            P4 q1a{p1[0], p1[1], p1[2], p1[3]};
            P4 q1b{p1[4], p1[5], p1[6], p1[7]};
            f16x8 pB00 = __builtin_bit_cast(f16x8, q0a);
            f16x8 pB01 = __builtin_bit_cast(f16x8, q0b);
            f16x8 pB10 = __builtin_bit_cast(f16x8, q1a);
            f16x8 pB11 = __builtin_bit_cast(f16x8, q1b);

            // --- both PV blocks ---
            out[0] = MFMA32F(av0, pB00, out[0]);
            out[1] = MFMA32F(av0, pB10, out[1]);
            out[0] = MFMA32F(av1, pB01, out[0]);
            out[1] = MFMA32F(av1, pB11, out[1]);

            // --- normalizer partial sums ---
            f16x2 sA = ((p0[0] + p0[1]) + (p0[2] + p0[3])) +
                       ((p0[4] + p0[5]) + (p0[6] + p0[7]));
            f16x2 sB = ((p1[0] + p1[1]) + (p1[2] + p1[3])) +
                       ((p1[4] + p1[5]) + (p1[6] + p1[7]));
            lsum[0] = __builtin_amdgcn_fdot2(sA, ONE2, lsum[0], false);
            lsum[1] = __builtin_amdgcn_fdot2(sB, ONE2, lsum[1], false);
        }
    }

    lred[w][lane]  = lsum[0];
    lred1[w][lane] = lsum[1];

    const int b = bh >> 2, hh = bh & 3;
#pragma unroll
    for (int qs = 0; qs < 2; ++qs) {
        __syncthreads();
        if (kh > 0) {
            float* r = red + (((kh - 1) * 2 + qg) * 64 + lane) * 20;
            *(f32x4*)(r + 0)  = (f32x4){out[qs][0], out[qs][1], out[qs][2], out[qs][3]};
            *(f32x4*)(r + 4)  = (f32x4){out[qs][4], out[qs][5], out[qs][6], out[qs][7]};
            *(f32x4*)(r + 8)  = (f32x4){out[qs][8], out[qs][9], out[qs][10], out[qs][11]};
            *(f32x4*)(r + 12) = (f32x4){out[qs][12], out[qs][13], out[qs][14], out[qs][15]};
        }
        __syncthreads();
        if (kh == 0) {
            f32x16 o = out[qs];
#pragma unroll
            for (int j = 0; j < 3; ++j) {
                const float* r = red + ((j * 2 + qg) * 64 + lane) * 20;
#pragma unroll
                for (int i = 0; i < 16; ++i) o[i] += r[i];
            }
            float l = 0.f;
            const float (*lr)[64] = qs ? lred1 : lred;
#pragma unroll
            for (int j = 0; j < 4; ++j)
                l += lr[j * 2 + qg][l31] + lr[j * 2 + qg][32 + l31];
            float inv = __builtin_amdgcn_rcpf(l);
            f16* Ob = O + ((size_t)b * N + qbase + qs * 32 + l31) * CDIM + hh * DH;
#pragma unroll
            for (int rg = 0; rg < 4; ++rg) {
                const int d0 = rg * 8 + h * 4;
                f16x4 v = {(f16)(o[rg * 4 + 0] * inv), (f16)(o[rg * 4 + 1] * inv),
                           (f16)(o[rg * 4 + 2] * inv), (f16)(o[rg * 4 + 3] * inv)};
                *(f16x4*)(Ob + d0) = v;
            }
        }
    }
}

// ---------------- output projection (r8 verbatim) ---------------------------
__global__ __launch_bounds__(256) void proj_o(const f16* __restrict__ A,
                                              const float* __restrict__ wo,
                                              const float* __restrict__ bo,
                                              float* __restrict__ out) {
    const int b = blockIdx.y;
    const int n0 = blockIdx.x * 64;
    __shared__ __align__(16) f16 aT[64][136];   // [n][c]
    __shared__ __align__(16) f16 Wl[64 * 136];  // only this z's 64 rows
    const int tid = threadIdx.x;
    const f16* Ab = A + (size_t)b * N * CDIM;
    const float* Wm = wo + (size_t)blockIdx.z * 64 * 128;  // wo half, f32
    for (int i = tid; i < 64 * 16; i += 256) {  // 4 b128 copies per thread
        int c8 = (i & 15) * 8, n = i >> 4;
        *(f16x8*)&aT[n][c8] = *(const f16x8*)&Ab[(size_t)(n0 + n) * CDIM + c8];
    }
    for (int i = tid; i < 1024; i += 256) {  // stage wo, f32 -> f16 inline
        int row = i >> 4, c8 = (i & 15) * 8;
        const float4 fa = *(const float4*)&Wm[row * 128 + c8];
        const float4 fb = *(const float4*)&Wm[row * 128 + c8 + 4];
        f16x8 v8 = {(f16)fa.x, (f16)fa.y, (f16)fa.z, (f16)fa.w,
                    (f16)fb.x, (f16)fb.y, (f16)fb.z, (f16)fb.w};
        *(f16x8*)&Wl[row * 136 + c8] = v8;
    }
    __syncthreads();

    const int lane = tid & 63, w = tid >> 6;
    const int cr = lane & 15, quad = lane >> 4;
    const int ot = blockIdx.z * 4 + w;
    const int o = ot * 16 + cr;
    const float bov = bo[o];
    float* orow = out + (size_t)(b * CDIM + o) * N + n0;

    for (int nt = 0; nt < 4; ++nt) {
        f16x8 bfr[4];
#pragma unroll
        for (int ks = 0; ks < 4; ++ks)
            bfr[ks] = *(const f16x8*)&aT[nt * 16 + cr][ks * 32 + quad * 8];
        f32x4 acc = {0.f, 0.f, 0.f, 0.f};
#pragma unroll
        for (int ks = 0; ks < 4; ++ks) {
            f16x8 afr = *(const f16x8*)&Wl[(w * 16 + cr) * 136 + ks * 32 + quad * 8];
            acc = MFMA16F(bfr[ks], afr, acc);  // D[n][o]
        }
        f32x4 res = {acc[0] + bov, acc[1] + bov, acc[2] + bov, acc[3] + bov};
        *(f32x4*)(orow + nt * 16 + quad * 4) = res;
    }
}

// ---------------- launch ----------------
extern "C" void kernel_launch(void* const* d_in, const int* in_sizes, int n_in,
                              void* d_out, int out_size, void* d_ws, size_t ws_size,
                              hipStream_t stream) {
    const float* x  = (const float*)d_in[0];
    const float* wq = (const float*)d_in[1];
    const float* wk = (const float*)d_in[2];
    const float* wv = (const float*)d_in[3];
    const float* wo = (const float*)d_in[4];
    const float* bo = (const float*)d_in[5];

    char* ws = (char*)d_ws;
    f16* Q = (f16*)(ws);                       // 4 MB  [bh][n][32]
    f16* K = (f16*)(ws + ((size_t)4 << 20));   // 4 MB  [bh][n][32]
    f16* V = (f16*)(ws + ((size_t)8 << 20));   // 4 MB  [bh][tile][d32][kperm64]
    f16* A = (f16*)(ws + ((size_t)12 << 20));  // 4 MB  [b][n][128]

    proj_qkv<<<dim3(64, 4, 3), 256, 0, stream>>>(x, wq, wk, wv, Q, K, V);
    flash<<<512, 512, 0, stream>>>(Q, K, V, A);
    proj_o<<<dim3(64, 4, 2), 256, 0, stream>>>(A, wo, bo, (float*)d_out);
}

// Round 12
// 127.434 us; speedup vs baseline: 1.0222x; 1.0222x over previous
//
#include <hip/hip_runtime.h>
#include <cstdint>

typedef _Float16 f16;
typedef f16 f16x2 __attribute__((ext_vector_type(2)));
typedef f16 f16x4 __attribute__((ext_vector_type(4)));
typedef f16 f16x8 __attribute__((ext_vector_type(8)));
typedef float f32x4 __attribute__((ext_vector_type(4)));
typedef float f32x16 __attribute__((ext_vector_type(16)));

#define MFMA16F(a, b, c) __builtin_amdgcn_mfma_f32_16x16x32_f16(a, b, c, 0, 0, 0)
#define MFMA32F(a, b, c) __builtin_amdgcn_mfma_f32_32x32x16_f16(a, b, c, 0, 0, 0)

static constexpr int N = 4096;    // 64*64 tokens
static constexpr int CDIM = 128;  // channels
static constexpr int NH = 4;      // heads
static constexpr int DH = 32;     // dim per head

__device__ __forceinline__ f16x2 cvt_pk(float a, float b) {
    return __builtin_bit_cast(f16x2, __builtin_amdgcn_cvt_pkrtz(a, b));
}

// ---------------- QKV projection (r8 verbatim: split-z, inline W convert) ---
__global__ __launch_bounds__(256) void proj_qkv(const float* __restrict__ x,
                                                const float* __restrict__ wq,
                                                const float* __restrict__ wk,
                                                const float* __restrict__ wv,
                                                f16* __restrict__ Q,
                                                f16* __restrict__ K,
                                                f16* __restrict__ V) {
    const int b = blockIdx.y;
    const int wt = blockIdx.z;
    const int n0 = blockIdx.x * 64;
    __shared__ __align__(16) f16 xT[64][136];   // [n][c], padded
    __shared__ __align__(16) f16 Wl[128 * 136]; // W rows padded to 136
    const int tid = threadIdx.x;
    const float* xb = x + (size_t)b * CDIM * N;
    const float* Wsrc = (wt == 0) ? wq : (wt == 1) ? wk : wv;
    const float wsc = (wt == 0) ? 0.17677669529663687f * 1.4426950408889634f : 1.0f;

    for (int i = tid; i < 512; i += 256) {  // 4 channels/iter -> b64 LDS writes
        const int n4 = (i & 15) * 4, c4 = (i >> 4) * 4;
        const float* xp = &xb[(size_t)c4 * N + n0 + n4];
        const float4 v0 = *(const float4*)(xp);
        const float4 v1 = *(const float4*)(xp + N);
        const float4 v2 = *(const float4*)(xp + 2 * N);
        const float4 v3 = *(const float4*)(xp + 3 * N);
        f16x4 w0 = {(f16)v0.x, (f16)v1.x, (f16)v2.x, (f16)v3.x};
        f16x4 w1 = {(f16)v0.y, (f16)v1.y, (f16)v2.y, (f16)v3.y};
        f16x4 w2 = {(f16)v0.z, (f16)v1.z, (f16)v2.z, (f16)v3.z};
        f16x4 w3 = {(f16)v0.w, (f16)v1.w, (f16)v2.w, (f16)v3.w};
        *(f16x4*)&xT[n4 + 0][c4] = w0;
        *(f16x4*)&xT[n4 + 1][c4] = w1;
        *(f16x4*)&xT[n4 + 2][c4] = w2;
        *(f16x4*)&xT[n4 + 3][c4] = w3;
    }
    for (int i = tid; i < 2048; i += 256) {  // stage W, f32 -> f16 inline
        int row = i >> 4, c8 = (i & 15) * 8;
        const float4 fa = *(const float4*)&Wsrc[row * 128 + c8];
        const float4 fb = *(const float4*)&Wsrc[row * 128 + c8 + 4];
        f16x8 v8 = {(f16)(fa.x * wsc), (f16)(fa.y * wsc), (f16)(fa.z * wsc), (f16)(fa.w * wsc),
                    (f16)(fb.x * wsc), (f16)(fb.y * wsc), (f16)(fb.z * wsc), (f16)(fb.w * wsc)};
        *(f16x8*)&Wl[row * 136 + c8] = v8;
    }
    __syncthreads();

    const int lane = tid & 63, w = tid >> 6;
    const int cr = lane & 15, quad = lane >> 4;
    const int sg = ((quad & 1) << 1) | (quad >> 1);  // V slot-group of quad

    for (int nt = 0; nt < 4; ++nt) {
        f16x8 bfr[4];
#pragma unroll
        for (int ks = 0; ks < 4; ++ks)
            bfr[ks] = *(const f16x8*)&xT[nt * 16 + cr][ks * 32 + quad * 8];
#pragma unroll
        for (int ot2 = 0; ot2 < 2; ++ot2) {
            int ot = w * 2 + ot2;
            f32x4 acc = {0.f, 0.f, 0.f, 0.f};
            if (wt < 2) {
                // D[o][n]: row(o)=ot*16+quad*4+r, col(n)=cr
#pragma unroll
                for (int ks = 0; ks < 4; ++ks) {
                    f16x8 afr = *(const f16x8*)&Wl[(ot * 16 + cr) * 136 + ks * 32 + quad * 8];
                    acc = MFMA16F(afr, bfr[ks], acc);
                }
                f16* dst = (wt == 0) ? Q : K;
                int n = n0 + nt * 16 + cr;
                int o0 = ot * 16 + quad * 4, hh = o0 >> 5, d0 = o0 & 31;
                f16x4 v4 = {(f16)acc[0], (f16)acc[1], (f16)acc[2], (f16)acc[3]};
                *(f16x4*)(dst + (((size_t)(b * NH + hh) * N + n) * DH + d0)) = v4;
            } else {
                // swapped: D[key][o]: row(key off)=quad*4+r, col(o)=ot*16+cr
#pragma unroll
                for (int ks = 0; ks < 4; ++ks) {
                    f16x8 afr = *(const f16x8*)&Wl[(ot * 16 + cr) * 136 + ks * 32 + quad * 8];
                    acc = MFMA16F(bfr[ks], afr, acc);
                }
                int o = ot * 16 + cr, hh = o >> 5, d = o & 31;
                f16x4 v4 = {(f16)acc[0], (f16)acc[1], (f16)acc[2], (f16)acc[3]};
                *(f16x4*)(V + ((size_t)(b * NH + hh) * 64 + blockIdx.x) * 2048 +
                          d * 64 + nt * 16 + sg * 4) = v4;
            }
        }
    }
}

// ---------------- flash attention (r10 verbatim: best measured 46.9 us) -----
__global__ __launch_bounds__(512, 4) void flash(const f16* __restrict__ Q,
                                                const f16* __restrict__ K,
                                                const f16* __restrict__ V,
                                                f16* __restrict__ O) {
    const int gid = blockIdx.x;
    const int bh = gid & 15;
    const int qblk = gid >> 4;  // 0..31
    const int tid = threadIdx.x;
    const int w = tid >> 6, lane = tid & 63;
    const int l31 = lane & 31, h = lane >> 5;
    const int qg = w & 1, kh = w >> 1;
    const int qbase = qblk * 128 + qg * 64;

    __shared__ __align__(16) f16 Kl[4][64 * 40];  // key rows stride 40
    __shared__ __align__(16) f16 Vl[4][32 * 72];  // d rows stride 72
    __shared__ float lred[8][64];
    __shared__ float lred1[8][64];

    const f16* Qb = Q + (size_t)bh * N * DH;
    const f16* Kb = K + (size_t)bh * N * DH;
    const f16* Vt = V + (size_t)bh * 64 * 2048;

    const int qtr = tid >> 7, t = tid & 127;
    const f16* ksrc = Kb + (size_t)(qtr * 16) * 2048 + t * 16;
    const f16* vsrc = Vt + (size_t)(qtr * 16) * 2048 + t * 16;
    f16* kdst = &Kl[qtr][(t >> 1) * 40 + (t & 1) * 16];
    f16* vdst = &Vl[qtr][(t >> 2) * 72 + (t & 3) * 16];

    f16x8 qf[2][2];  // [qs][d-half]
#pragma unroll
    for (int qs = 0; qs < 2; ++qs)
#pragma unroll
        for (int dh = 0; dh < 2; ++dh)
            qf[qs][dh] = *(const f16x8*)&Qb[(qbase + qs * 32 + l31) * DH + dh * 16 + h * 8];

    const f16x2 C3 = {(f16)0.05550411f, (f16)0.05550411f};
    const f16x2 C2 = {(f16)0.24022651f, (f16)0.24022651f};
    const f16x2 C1 = {(f16)0.69314718f, (f16)0.69314718f};
    const f16x2 ONE2 = {(f16)1.0f, (f16)1.0f};

    f32x16 out[2] = {};          // [qs]: out^T[d=row][q=col]
    float lsum[2] = {0.f, 0.f};  // per-lane partial normalizer

    // prefetch tile 0
    f16x8 kr0 = *(const f16x8*)(ksrc);
    f16x8 kr1 = *(const f16x8*)(ksrc + 8);
    f16x8 vr0 = *(const f16x8*)(vsrc);
    f16x8 vr1 = *(const f16x8*)(vsrc + 8);

    for (int kt = 0; kt < 16; ++kt) {
        __syncthreads();
        *(f16x8*)(kdst)     = kr0;
        *(f16x8*)(kdst + 8) = kr1;
        *(f16x8*)(vdst)     = vr0;
        *(f16x8*)(vdst + 8) = vr1;
        __syncthreads();
        if (kt < 15) {
            const size_t off = (size_t)(kt + 1) * 2048;
            kr0 = *(const f16x8*)(ksrc + off);
            kr1 = *(const f16x8*)(ksrc + off + 8);
            vr0 = *(const f16x8*)(vsrc + off);
            vr1 = *(const f16x8*)(vsrc + off + 8);
        }
        const f16* Kc = &Kl[kh][0];
        const f16* Vc = &Vl[kh][0];

#pragma unroll
        for (int g2 = 0; g2 < 2; ++g2) {
            f16x8 kf0 = *(const f16x8*)&Kc[(g2 * 32 + l31) * 40 + h * 8];
            f16x8 kf1 = *(const f16x8*)&Kc[(g2 * 32 + l31) * 40 + 16 + h * 8];
            f16x8 av0 = *(const f16x8*)&Vc[l31 * 72 + g2 * 32 + h * 8];
            f16x8 av1 = *(const f16x8*)&Vc[l31 * 72 + g2 * 32 + 16 + h * 8];

            // --- both qs QK^T blocks (independent chains) ---
            f32x16 sc0 = {};
            f32x16 sc1 = {};
            sc0 = MFMA32F(kf0, qf[0][0], sc0);
            sc1 = MFMA32F(kf0, qf[1][0], sc1);
            sc0 = MFMA32F(kf1, qf[0][1], sc0);
            sc1 = MFMA32F(kf1, qf[1][1], sc1);

            // --- both exp polys, interleaved ---
            f16x2 p0[8], p1[8];
#pragma unroll
            for (int i = 0; i < 8; ++i) {
                f16x2 x0 = cvt_pk(sc0[2 * i], sc0[2 * i + 1]);
                f16x2 x1 = cvt_pk(sc1[2 * i], sc1[2 * i + 1]);
                f16x2 t0 = x0 * C3 + C2;
                f16x2 t1 = x1 * C3 + C2;
                t0 = x0 * t0 + C1;
                t1 = x1 * t1 + C1;
                p0[i] = x0 * t0 + ONE2;
                p1[i] = x1 * t1 + ONE2;
            }
            struct P4 { f16x2 a, b, c, d; };
            P4 q0a{p0[0], p0[1], p0[2], p0[3]};
            P4 q0b{p0[4], p0[5], p0[6], p0[7]};
            P4 q1a{p1[0], p1[1], p1[2], p1[3]};
            P4 q1b{p1[4], p1[5], p1[6], p1[7]};
            f16x8 pB00 = __builtin_bit_cast(f16x8, q0a);
            f16x8 pB01 = __builtin_bit_cast(f16x8, q0b);
            f16x8 pB10 = __builtin_bit_cast(f16x8, q1a);
            f16x8 pB11 = __builtin_bit_cast(f16x8, q1b);

            // --- both PV blocks ---
            out[0] = MFMA32F(av0, pB00, out[0]);
            out[1] = MFMA32F(av0, pB10, out[1]);
            out[0] = MFMA32F(av1, pB01, out[0]);
            out[1] = MFMA32F(av1, pB11, out[1]);

            // --- normalizer partial sums ---
            f16x2 sA = ((p0[0] + p0[1]) + (p0[2] + p0[3])) +
                       ((p0[4] + p0[5]) + (p0[6] + p0[7]));
            f16x2 sB = ((p1[0] + p1[1]) + (p1[2] + p1[3])) +
                       ((p1[4] + p1[5]) + (p1[6] + p1[7]));
            lsum[0] = __builtin_amdgcn_fdot2(sA, ONE2, lsum[0], false);
            lsum[1] = __builtin_amdgcn_fdot2(sB, ONE2, lsum[1], false);
        }
    }

    lred[w][lane]  = lsum[0];
    lred1[w][lane] = lsum[1];

    float* red = (float*)&Kl[0][0];  // 6*64*20*4 = 30720 B overlay
    const int b = bh >> 2, hh = bh & 3;
#pragma unroll
    for (int qs = 0; qs < 2; ++qs) {
        __syncthreads();
        if (kh > 0) {
            float* r = red + (((kh - 1) * 2 + qg) * 64 + lane) * 20;
            *(f32x4*)(r + 0)  = (f32x4){out[qs][0], out[qs][1], out[qs][2], out[qs][3]};
            *(f32x4*)(r + 4)  = (f32x4){out[qs][4], out[qs][5], out[qs][6], out[qs][7]};
            *(f32x4*)(r + 8)  = (f32x4){out[qs][8], out[qs][9], out[qs][10], out[qs][11]};
            *(f32x4*)(r + 12) = (f32x4){out[qs][12], out[qs][13], out[qs][14], out[qs][15]};
        }
        __syncthreads();
        if (kh == 0) {
            f32x16 o = out[qs];
#pragma unroll
            for (int j = 0; j < 3; ++j) {
                const float* r = red + ((j * 2 + qg) * 64 + lane) * 20;
#pragma unroll
                for (int i = 0; i < 16; ++i) o[i] += r[i];
            }
            float l = 0.f;
            const float (*lr)[64] = qs ? lred1 : lred;
#pragma unroll
            for (int j = 0; j < 4; ++j)
                l += lr[j * 2 + qg][l31] + lr[j * 2 + qg][32 + l31];
            float inv = __builtin_amdgcn_rcpf(l);
            f16* Ob = O + ((size_t)b * N + qbase + qs * 32 + l31) * CDIM + hh * DH;
#pragma unroll
            for (int rg = 0; rg < 4; ++rg) {
                const int d0 = rg * 8 + h * 4;
                f16x4 v = {(f16)(o[rg * 4 + 0] * inv), (f16)(o[rg * 4 + 1] * inv),
                           (f16)(o[rg * 4 + 2] * inv), (f16)(o[rg * 4 + 3] * inv)};
                *(f16x4*)(Ob + d0) = v;
            }
        }
    }
}

// ---------------- output projection (r8 verbatim) ---------------------------
__global__ __launch_bounds__(256) void proj_o(const f16* __restrict__ A,
                                              const float* __restrict__ wo,
                                              const float* __restrict__ bo,
                                              float* __restrict__ out) {
    const int b = blockIdx.y;
    const int n0 = blockIdx.x * 64;
    __shared__ __align__(16) f16 aT[64][136];   // [n][c]
    __shared__ __align__(16) f16 Wl[64 * 136];  // only this z's 64 rows
    const int tid = threadIdx.x;
    const f16* Ab = A + (size_t)b * N * CDIM;
    const float* Wm = wo + (size_t)blockIdx.z * 64 * 128;  // wo half, f32
    for (int i = tid; i < 64 * 16; i += 256) {  // 4 b128 copies per thread
        int c8 = (i & 15) * 8, n = i >> 4;
        *(f16x8*)&aT[n][c8] = *(const f16x8*)&Ab[(size_t)(n0 + n) * CDIM + c8];
    }
    for (int i = tid; i < 1024; i += 256) {  // stage wo, f32 -> f16 inline
        int row = i >> 4, c8 = (i & 15) * 8;
        const float4 fa = *(const float4*)&Wm[row * 128 + c8];
        const float4 fb = *(const float4*)&Wm[row * 128 + c8 + 4];
        f16x8 v8 = {(f16)fa.x, (f16)fa.y, (f16)fa.z, (f16)fa.w,
                    (f16)fb.x, (f16)fb.y, (f16)fb.z, (f16)fb.w};
        *(f16x8*)&Wl[row * 136 + c8] = v8;
    }
    __syncthreads();

    const int lane = tid & 63, w = tid >> 6;
    const int cr = lane & 15, quad = lane >> 4;
    const int ot = blockIdx.z * 4 + w;
    const int o = ot * 16 + cr;
    const float bov = bo[o];
    float* orow = out + (size_t)(b * CDIM + o) * N + n0;

    for (int nt = 0; nt < 4; ++nt) {
        f16x8 bfr[4];
#pragma unroll
        for (int ks = 0; ks < 4; ++ks)
            bfr[ks] = *(const f16x8*)&aT[nt * 16 + cr][ks * 32 + quad * 8];
        f32x4 acc = {0.f, 0.f, 0.f, 0.f};
#pragma unroll
        for (int ks = 0; ks < 4; ++ks) {
            f16x8 afr = *(const f16x8*)&Wl[(w * 16 + cr) * 136 + ks * 32 + quad * 8];
            acc = MFMA16F(bfr[ks], afr, acc);  // D[n][o]
        }
        f32x4 res = {acc[0] + bov, acc[1] + bov, acc[2] + bov, acc[3] + bov};
        *(f32x4*)(orow + nt * 16 + quad * 4) = res;
    }
}

// ---------------- launch ----------------
extern "C" void kernel_launch(void* const* d_in, const int* in_sizes, int n_in,
                              void* d_out, int out_size, void* d_ws, size_t ws_size,
                              hipStream_t stream) {
    const float* x  = (const float*)d_in[0];
    const float* wq = (const float*)d_in[1];
    const float* wk = (const float*)d_in[2];
    const float* wv = (const float*)d_in[3];
    const float* wo = (const float*)d_in[4];
    const float* bo = (const float*)d_in[5];

    char* ws = (char*)d_ws;
    f16* Q = (f16*)(ws);                       // 4 MB  [bh][n][32]
    f16* K = (f16*)(ws + ((size_t)4 << 20));   // 4 MB  [bh][n][32]
    f16* V = (f16*)(ws + ((size_t)8 << 20));   // 4 MB  [bh][tile][d32][kperm64]
    f16* A = (f16*)(ws + ((size_t)12 << 20));  // 4 MB  [b][n][128]

    proj_qkv<<<dim3(64, 4, 3), 256, 0, stream>>>(x, wq, wk, wv, Q, K, V);
    flash<<<512, 512, 0, stream>>>(Q, K, V, A);
    proj_o<<<dim3(64, 4, 2), 256, 0, stream>>>(A, wo, bo, (float*)d_out);
}

// Round 13
// 123.758 us; speedup vs baseline: 1.0526x; 1.0297x over previous
//
#include <hip/hip_runtime.h>
#include <cstdint>

typedef _Float16 f16;
typedef f16 f16x2 __attribute__((ext_vector_type(2)));
typedef f16 f16x4 __attribute__((ext_vector_type(4)));
typedef f16 f16x8 __attribute__((ext_vector_type(8)));
typedef float f32x4 __attribute__((ext_vector_type(4)));
typedef float f32x16 __attribute__((ext_vector_type(16)));

#define MFMA16F(a, b, c) __builtin_amdgcn_mfma_f32_16x16x32_f16(a, b, c, 0, 0, 0)
#define MFMA32F(a, b, c) __builtin_amdgcn_mfma_f32_32x32x16_f16(a, b, c, 0, 0, 0)

static constexpr int N = 4096;    // 64*64 tokens
static constexpr int CDIM = 128;  // channels
static constexpr int NH = 4;      // heads
static constexpr int DH = 32;     // dim per head

__device__ __forceinline__ f16x2 cvt_pk(float a, float b) {
    return __builtin_bit_cast(f16x2, __builtin_amdgcn_cvt_pkrtz(a, b));
}

// ---------------- QKV projection -------------------------------------------
// x: [b][128][4096] f32; weights staged f32->f16 inline (wq pre-scaled by
// 32^-0.5 * log2(e)). Q,K: [b*4+h][n][32] f16 ;
// V TILED+PERMUTED [bh][tile][d32][kperm64] f16.
__global__ __launch_bounds__(256) void proj_qkv(const float* __restrict__ x,
                                                const float* __restrict__ wq,
                                                const float* __restrict__ wk,
                                                const float* __restrict__ wv,
                                                f16* __restrict__ Q,
                                                f16* __restrict__ K,
                                                f16* __restrict__ V) {
    const int b = blockIdx.y;
    const int wt = blockIdx.z;
    const int n0 = blockIdx.x * 64;
    __shared__ __align__(16) f16 xT[64][136];   // [n][c], padded
    __shared__ __align__(16) f16 Wl[128 * 136]; // W rows padded to 136
    const int tid = threadIdx.x;
    const float* xb = x + (size_t)b * CDIM * N;
    const float* Wsrc = (wt == 0) ? wq : (wt == 1) ? wk : wv;
    const float wsc = (wt == 0) ? 0.17677669529663687f * 1.4426950408889634f : 1.0f;

    for (int i = tid; i < 512; i += 256) {  // 4 channels/iter -> b64 LDS writes
        const int n4 = (i & 15) * 4, c4 = (i >> 4) * 4;
        const float* xp = &xb[(size_t)c4 * N + n0 + n4];
        const float4 v0 = *(const float4*)(xp);
        const float4 v1 = *(const float4*)(xp + N);
        const float4 v2 = *(const float4*)(xp + 2 * N);
        const float4 v3 = *(const float4*)(xp + 3 * N);
        f16x4 w0 = {(f16)v0.x, (f16)v1.x, (f16)v2.x, (f16)v3.x};
        f16x4 w1 = {(f16)v0.y, (f16)v1.y, (f16)v2.y, (f16)v3.y};
        f16x4 w2 = {(f16)v0.z, (f16)v1.z, (f16)v2.z, (f16)v3.z};
        f16x4 w3 = {(f16)v0.w, (f16)v1.w, (f16)v2.w, (f16)v3.w};
        *(f16x4*)&xT[n4 + 0][c4] = w0;
        *(f16x4*)&xT[n4 + 1][c4] = w1;
        *(f16x4*)&xT[n4 + 2][c4] = w2;
        *(f16x4*)&xT[n4 + 3][c4] = w3;
    }
    for (int i = tid; i < 2048; i += 256) {  // stage W, f32 -> f16 inline
        int row = i >> 4, c8 = (i & 15) * 8;
        const float4 fa = *(const float4*)&Wsrc[row * 128 + c8];
        const float4 fb = *(const float4*)&Wsrc[row * 128 + c8 + 4];
        f16x8 v8 = {(f16)(fa.x * wsc), (f16)(fa.y * wsc), (f16)(fa.z * wsc), (f16)(fa.w * wsc),
                    (f16)(fb.x * wsc), (f16)(fb.y * wsc), (f16)(fb.z * wsc), (f16)(fb.w * wsc)};
        *(f16x8*)&Wl[row * 136 + c8] = v8;
    }
    __syncthreads();

    const int lane = tid & 63, w = tid >> 6;
    const int cr = lane & 15, quad = lane >> 4;
    const int sg = ((quad & 1) << 1) | (quad >> 1);  // V slot-group of quad

    for (int nt = 0; nt < 4; ++nt) {
        f16x8 bfr[4];
#pragma unroll
        for (int ks = 0; ks < 4; ++ks)
            bfr[ks] = *(const f16x8*)&xT[nt * 16 + cr][ks * 32 + quad * 8];
#pragma unroll
        for (int ot2 = 0; ot2 < 2; ++ot2) {
            int ot = w * 2 + ot2;
            f32x4 acc = {0.f, 0.f, 0.f, 0.f};
            if (wt < 2) {
                // D[o][n]: row(o)=ot*16+quad*4+r, col(n)=cr
#pragma unroll
                for (int ks = 0; ks < 4; ++ks) {
                    f16x8 afr = *(const f16x8*)&Wl[(ot * 16 + cr) * 136 + ks * 32 + quad * 8];
                    acc = MFMA16F(afr, bfr[ks], acc);
                }
                f16* dst = (wt == 0) ? Q : K;
                int n = n0 + nt * 16 + cr;
                int o0 = ot * 16 + quad * 4, hh = o0 >> 5, d0 = o0 & 31;
                f16x4 v4 = {(f16)acc[0], (f16)acc[1], (f16)acc[2], (f16)acc[3]};
                *(f16x4*)(dst + (((size_t)(b * NH + hh) * N + n) * DH + d0)) = v4;
            } else {
                // swapped: D[key][o]: row(key off)=quad*4+r, col(o)=ot*16+cr
#pragma unroll
                for (int ks = 0; ks < 4; ++ks) {
                    f16x8 afr = *(const f16x8*)&Wl[(ot * 16 + cr) * 136 + ks * 32 + quad * 8];
                    acc = MFMA16F(bfr[ks], afr, acc);
                }
                int o = ot * 16 + cr, hh = o >> 5, d = o & 31;
                f16x4 v4 = {(f16)acc[0], (f16)acc[1], (f16)acc[2], (f16)acc[3]};
                *(f16x4*)(V + ((size_t)(b * NH + hh) * 64 + blockIdx.x) * 2048 +
                          d * 64 + nt * 16 + sg * 4) = v4;
            }
        }
    }
}

// ---------------- flash attention (r7 schedule + T5 setprio on MFMA) --------
__global__ __launch_bounds__(512, 4) void flash(const f16* __restrict__ Q,
                                                const f16* __restrict__ K,
                                                const f16* __restrict__ V,
                                                f16* __restrict__ O) {
    const int gid = blockIdx.x;
    const int bh = gid & 15;
    const int qblk = gid >> 4;  // 0..31
    const int tid = threadIdx.x;
    const int w = tid >> 6, lane = tid & 63;
    const int l31 = lane & 31, h = lane >> 5;
    const int qg = w & 1, kh = w >> 1;
    const int qbase = qblk * 128 + qg * 64;

    __shared__ __align__(16) f16 Kl[4][64 * 40];  // key rows stride 40
    __shared__ __align__(16) f16 Vl[4][32 * 72];  // d rows stride 72
    __shared__ float lred[8][64];
    __shared__ float lred1[8][64];

    const f16* Qb = Q + (size_t)bh * N * DH;
    const f16* Kb = K + (size_t)bh * N * DH;
    const f16* Vt = V + (size_t)bh * 64 * 2048;

    const int qtr = tid >> 7, t = tid & 127;
    const f16* ksrc = Kb + (size_t)(qtr * 16) * 2048 + t * 16;
    const f16* vsrc = Vt + (size_t)(qtr * 16) * 2048 + t * 16;
    f16* kdst = &Kl[qtr][(t >> 1) * 40 + (t & 1) * 16];
    f16* vdst = &Vl[qtr][(t >> 2) * 72 + (t & 3) * 16];

    f16x8 qf[2][2];  // [qs][d-half]
#pragma unroll
    for (int qs = 0; qs < 2; ++qs)
#pragma unroll
        for (int dh = 0; dh < 2; ++dh)
            qf[qs][dh] = *(const f16x8*)&Qb[(qbase + qs * 32 + l31) * DH + dh * 16 + h * 8];

    const f16x2 C3 = {(f16)0.05550411f, (f16)0.05550411f};
    const f16x2 C2 = {(f16)0.24022651f, (f16)0.24022651f};
    const f16x2 C1 = {(f16)0.69314718f, (f16)0.69314718f};
    const f16x2 ONE2 = {(f16)1.0f, (f16)1.0f};

    f32x16 out[2] = {};          // [qs]: out^T[d=row][q=col]
    float lsum[2] = {0.f, 0.f};  // per-lane partial normalizer

    // prefetch tile 0
    f16x8 kr0 = *(const f16x8*)(ksrc);
    f16x8 kr1 = *(const f16x8*)(ksrc + 8);
    f16x8 vr0 = *(const f16x8*)(vsrc);
    f16x8 vr1 = *(const f16x8*)(vsrc + 8);

    for (int kt = 0; kt < 16; ++kt) {
        __syncthreads();
        *(f16x8*)(kdst)     = kr0;
        *(f16x8*)(kdst + 8) = kr1;
        *(f16x8*)(vdst)     = vr0;
        *(f16x8*)(vdst + 8) = vr1;
        __syncthreads();
        if (kt < 15) {
            const size_t off = (size_t)(kt + 1) * 2048;
            kr0 = *(const f16x8*)(ksrc + off);
            kr1 = *(const f16x8*)(ksrc + off + 8);
            vr0 = *(const f16x8*)(vsrc + off);
            vr1 = *(const f16x8*)(vsrc + off + 8);
        }
        const f16* Kc = &Kl[kh][0];
        const f16* Vc = &Vl[kh][0];

#pragma unroll
        for (int g2 = 0; g2 < 2; ++g2) {
            f16x8 kf0 = *(const f16x8*)&Kc[(g2 * 32 + l31) * 40 + h * 8];
            f16x8 kf1 = *(const f16x8*)&Kc[(g2 * 32 + l31) * 40 + 16 + h * 8];
            f16x8 av0 = *(const f16x8*)&Vc[l31 * 72 + g2 * 32 + h * 8];
            f16x8 av1 = *(const f16x8*)&Vc[l31 * 72 + g2 * 32 + 16 + h * 8];

            // --- both qs QK^T blocks (independent chains) ---
            f32x16 sc0 = {};
            f32x16 sc1 = {};
            __builtin_amdgcn_s_setprio(1);
            sc0 = MFMA32F(kf0, qf[0][0], sc0);
            sc1 = MFMA32F(kf0, qf[1][0], sc1);
            sc0 = MFMA32F(kf1, qf[0][1], sc0);
            sc1 = MFMA32F(kf1, qf[1][1], sc1);
            __builtin_amdgcn_s_setprio(0);

            // --- both exp polys, interleaved ---
            f16x2 p0[8], p1[8];
#pragma unroll
            for (int i = 0; i < 8; ++i) {
                f16x2 x0 = cvt_pk(sc0[2 * i], sc0[2 * i + 1]);
                f16x2 x1 = cvt_pk(sc1[2 * i], sc1[2 * i + 1]);
                f16x2 t0 = x0 * C3 + C2;
                f16x2 t1 = x1 * C3 + C2;
                t0 = x0 * t0 + C1;
                t1 = x1 * t1 + C1;
                p0[i] = x0 * t0 + ONE2;
                p1[i] = x1 * t1 + ONE2;
            }
            struct P4 { f16x2 a, b, c, d; };
            P4 q0a{p0[0], p0[1], p0[2], p0[3]};
            P4 q0b{p0[4], p0[5], p0[6], p0[7]};
            P4 q1a{p1[0], p1[1], p1[2], p1[3]};
            P4 q1b{p1[4], p1[5], p1[6], p1[7]};
            f16x8 pB00 = __builtin_bit_cast(f16x8, q0a);
            f16x8 pB01 = __builtin_bit_cast(f16x8, q0b);
            f16x8 pB10 = __builtin_bit_cast(f16x8, q1a);
            f16x8 pB11 = __builtin_bit_cast(f16x8, q1b);

            // --- both PV blocks ---
            __builtin_amdgcn_s_setprio(1);
            out[0] = MFMA32F(av0, pB00, out[0]);
            out[1] = MFMA32F(av0, pB10, out[1]);
            out[0] = MFMA32F(av1, pB01, out[0]);
            out[1] = MFMA32F(av1, pB11, out[1]);
            __builtin_amdgcn_s_setprio(0);

            // --- normalizer partial sums ---
            f16x2 sA = ((p0[0] + p0[1]) + (p0[2] + p0[3])) +
                       ((p0[4] + p0[5]) + (p0[6] + p0[7]));
            f16x2 sB = ((p1[0] + p1[1]) + (p1[2] + p1[3])) +
                       ((p1[4] + p1[5]) + (p1[6] + p1[7]));
            lsum[0] = __builtin_amdgcn_fdot2(sA, ONE2, lsum[0], false);
            lsum[1] = __builtin_amdgcn_fdot2(sB, ONE2, lsum[1], false);
        }
    }

    lred[w][lane]  = lsum[0];
    lred1[w][lane] = lsum[1];

    float* red = (float*)&Kl[0][0];  // 6*64*20*4 = 30720 B overlay
    const int b = bh >> 2, hh = bh & 3;
#pragma unroll
    for (int qs = 0; qs < 2; ++qs) {
        __syncthreads();
        if (kh > 0) {
            float* r = red + (((kh - 1) * 2 + qg) * 64 + lane) * 20;
            *(f32x4*)(r + 0)  = (f32x4){out[qs][0], out[qs][1], out[qs][2], out[qs][3]};
            *(f32x4*)(r + 4)  = (f32x4){out[qs][4], out[qs][5], out[qs][6], out[qs][7]};
            *(f32x4*)(r + 8)  = (f32x4){out[qs][8], out[qs][9], out[qs][10], out[qs][11]};
            *(f32x4*)(r + 12) = (f32x4){out[qs][12], out[qs][13], out[qs][14], out[qs][15]};
        }
        __syncthreads();
        if (kh == 0) {
            f32x16 o = out[qs];
#pragma unroll
            for (int j = 0; j < 3; ++j) {
                const float* r = red + ((j * 2 + qg) * 64 + lane) * 20;
#pragma unroll
                for (int i = 0; i < 16; ++i) o[i] += r[i];
            }
            float l = 0.f;
            const float (*lr)[64] = qs ? lred1 : lred;
#pragma unroll
            for (int j = 0; j < 4; ++j)
                l += lr[j * 2 + qg][l31] + lr[j * 2 + qg][32 + l31];
            float inv = __builtin_amdgcn_rcpf(l);
            f16* Ob = O + ((size_t)b * N + qbase + qs * 32 + l31) * CDIM + hh * DH;
#pragma unroll
            for (int rg = 0; rg < 4; ++rg) {
                const int d0 = rg * 8 + h * 4;
                f16x4 v = {(f16)(o[rg * 4 + 0] * inv), (f16)(o[rg * 4 + 1] * inv),
                           (f16)(o[rg * 4 + 2] * inv), (f16)(o[rg * 4 + 3] * inv)};
                *(f16x4*)(Ob + d0) = v;
            }
        }
    }
}

// ---------------- output projection -----------------------------------------
// A: [b][n][128] f16 ; out: [b][128][4096] f32 + bias. grid.z splits ot.
// wo staged f32->f16 inline; only the 64 rows this z-block uses.
__global__ __launch_bounds__(256) void proj_o(const f16* __restrict__ A,
                                              const float* __restrict__ wo,
                                              const float* __restrict__ bo,
                                              float* __restrict__ out) {
    const int b = blockIdx.y;
    const int n0 = blockIdx.x * 64;
    __shared__ __align__(16) f16 aT[64][136];   // [n][c]
    __shared__ __align__(16) f16 Wl[64 * 136];  // only this z's 64 rows
    const int tid = threadIdx.x;
    const f16* Ab = A + (size_t)b * N * CDIM;
    const float* Wm = wo + (size_t)blockIdx.z * 64 * 128;  // wo half, f32
    for (int i = tid; i < 64 * 16; i += 256) {  // 4 b128 copies per thread
        int c8 = (i & 15) * 8, n = i >> 4;
        *(f16x8*)&aT[n][c8] = *(const f16x8*)&Ab[(size_t)(n0 + n) * CDIM + c8];
    }
    for (int i = tid; i < 1024; i += 256) {  // stage wo, f32 -> f16 inline
        int row = i >> 4, c8 = (i & 15) * 8;
        const float4 fa = *(const float4*)&Wm[row * 128 + c8];
        const float4 fb = *(const float4*)&Wm[row * 128 + c8 + 4];
        f16x8 v8 = {(f16)fa.x, (f16)fa.y, (f16)fa.z, (f16)fa.w,
                    (f16)fb.x, (f16)fb.y, (f16)fb.z, (f16)fb.w};
        *(f16x8*)&Wl[row * 136 + c8] = v8;
    }
    __syncthreads();

    const int lane = tid & 63, w = tid >> 6;
    const int cr = lane & 15, quad = lane >> 4;
    const int ot = blockIdx.z * 4 + w;
    const int o = ot * 16 + cr;
    const float bov = bo[o];
    float* orow = out + (size_t)(b * CDIM + o) * N + n0;

    for (int nt = 0; nt < 4; ++nt) {
        f16x8 bfr[4];
#pragma unroll
        for (int ks = 0; ks < 4; ++ks)
            bfr[ks] = *(const f16x8*)&aT[nt * 16 + cr][ks * 32 + quad * 8];
        f32x4 acc = {0.f, 0.f, 0.f, 0.f};
#pragma unroll
        for (int ks = 0; ks < 4; ++ks) {
            f16x8 afr = *(const f16x8*)&Wl[(w * 16 + cr) * 136 + ks * 32 + quad * 8];
            acc = MFMA16F(bfr[ks], afr, acc);  // D[n][o]
        }
        f32x4 res = {acc[0] + bov, acc[1] + bov, acc[2] + bov, acc[3] + bov};
        *(f32x4*)(orow + nt * 16 + quad * 4) = res;
    }
}

// ---------------- launch ----------------
extern "C" void kernel_launch(void* const* d_in, const int* in_sizes, int n_in,
                              void* d_out, int out_size, void* d_ws, size_t ws_size,
                              hipStream_t stream) {
    const float* x  = (const float*)d_in[0];
    const float* wq = (const float*)d_in[1];
    const float* wk = (const float*)d_in[2];
    const float* wv = (const float*)d_in[3];
    const float* wo = (const float*)d_in[4];
    const float* bo = (const float*)d_in[5];

    char* ws = (char*)d_ws;
    f16* Q = (f16*)(ws);                       // 4 MB  [bh][n][32]
    f16* K = (f16*)(ws + ((size_t)4 << 20));   // 4 MB  [bh][n][32]
    f16* V = (f16*)(ws + ((size_t)8 << 20));   // 4 MB  [bh][tile][d32][kperm64]
    f16* A = (f16*)(ws + ((size_t)12 << 20));  // 4 MB  [b][n][128]

    proj_qkv<<<dim3(64, 4, 3), 256, 0, stream>>>(x, wq, wk, wv, Q, K, V);
    flash<<<512, 512, 0, stream>>>(Q, K, V, A);
    proj_o<<<dim3(64, 4, 2), 256, 0, stream>>>(A, wo, bo, (float*)d_out);
}